// Round 1
// baseline (2648.688 us; speedup 1.0000x reference)
//
#include <hip/hip_runtime.h>

typedef unsigned short u16;
typedef unsigned int u32;
typedef __bf16 bf16x8 __attribute__((ext_vector_type(8)));
typedef float f32x4 __attribute__((ext_vector_type(4)));

#define AS_STRIDE 136   // bf16 elems per LDS A-row (128 + 8 pad -> breaks bank alias)
#define TS_STRIDE 133   // f32 elems per LDS t-row

__device__ __forceinline__ u16 f2bf(float f) {
  union { float f; u32 u; } v; v.f = f;
  u32 r = v.u + 0x7fffu + ((v.u >> 16) & 1u);   // RNE
  return (u16)(r >> 16);
}

__device__ __forceinline__ float silu_f(float a) {
  return a / (1.f + __expf(-a));
}

// ---------------- weight prep: transpose + bf16-cast -------------------------
__global__ void prep_weights(const float* __restrict__ e_w1, const float* __restrict__ e_w2,
                             const float* __restrict__ n_w1, const float* __restrict__ n_w2,
                             u16* __restrict__ eW1T, u16* __restrict__ eW2T,
                             u16* __restrict__ nW1T, u16* __restrict__ nW2T) {
  int i = blockIdx.x * blockDim.x + threadIdx.x;
  const int s1 = 3 * 128 * 256;   // 98304
  const int s2 = 3 * 128 * 128;   // 49152
  if (i < s1) {                                  // eW1T[l][n][k] = e_w1[l][k][n], k<256
    int l = i / 32768, r = i % 32768, n = r >> 8, k = r & 255;
    eW1T[i] = f2bf(e_w1[l * 33408 + k * 128 + n]);
  } else if (i < s1 + s2) {                      // eW2T[l][n][k] = e_w2[l][k][n]
    int j = i - s1; int l = j / 16384, r = j % 16384, n = r >> 7, k = r & 127;
    eW2T[j] = f2bf(e_w2[l * 16384 + k * 128 + n]);
  } else if (i < s1 + s2 + s1) {                 // nW1T[l][n][k] = n_w1[l][k][n]
    int j = i - s1 - s2; int l = j / 32768, r = j % 32768, n = r >> 8, k = r & 255;
    nW1T[j] = f2bf(n_w1[l * 32768 + k * 128 + n]);
  } else if (i < 2 * s1 + 2 * s2) {              // nW2T[l][n][k] = n_w2[l][k][n]
    int j = i - 2 * s1 - s2; int l = j / 16384, r = j % 16384, n = r >> 7, k = r & 127;
    nW2T[j] = f2bf(n_w2[l * 16384 + k * 128 + n]);
  }
}

// ---------------- encoder: x(7) -> Linear -> LN -> SiLU -> Linear -> h(128) --
__global__ __launch_bounds__(128)
void encoder_kernel(const float* __restrict__ x,
                    const float* __restrict__ w1, const float* __restrict__ b1,
                    const float* __restrict__ g, const float* __restrict__ be,
                    const float* __restrict__ w2, const float* __restrict__ b2,
                    float* __restrict__ h, u16* __restrict__ hbf) {
  int node = blockIdx.x, j = threadIdx.x;
  __shared__ float sx[7];
  __shared__ float su[128];
  __shared__ float sred[4];
  if (j < 7) sx[j] = x[node * 7 + j];
  __syncthreads();
  float t = b1[j];
  #pragma unroll
  for (int k = 0; k < 7; k++) t += sx[k] * w1[k * 128 + j];
  float s = t, sq = t * t;
  for (int off = 32; off > 0; off >>= 1) { s += __shfl_down(s, off); sq += __shfl_down(sq, off); }
  int wid = j >> 6;
  if ((j & 63) == 0) { sred[wid * 2] = s; sred[wid * 2 + 1] = sq; }
  __syncthreads();
  float S = sred[0] + sred[2], SQ = sred[1] + sred[3];
  float mean = S * (1.f / 128.f);
  float rstd = rsqrtf(SQ * (1.f / 128.f) - mean * mean + 1e-5f);
  float a = (t - mean) * rstd * g[j] + be[j];
  su[j] = silu_f(a);
  __syncthreads();
  float o = b2[j];
  for (int k = 0; k < 128; k++) o += su[k] * w2[k * 128 + j];
  h[(size_t)node * 128 + j] = o;
  hbf[(size_t)node * 128 + j] = f2bf(o);
}

// ---------------- edge MLP + scatter-add (per layer) -------------------------
__global__ __launch_bounds__(256, 2)
void edge_mlp_kernel(const int* __restrict__ esrc, const int* __restrict__ edst,
                     const float* __restrict__ pos, const u16* __restrict__ hbf,
                     const u16* __restrict__ W1T,   // [128][256] bf16
                     const float* __restrict__ w1c, // [5][128] f32 (rows 256..260 of e_w1)
                     const float* __restrict__ b1,
                     const float* __restrict__ g, const float* __restrict__ be,
                     const u16* __restrict__ W2T,   // [128][128] bf16
                     const float* __restrict__ b2,
                     float* __restrict__ aggr) {
  __shared__ int s_src[64], s_dst[64];
  __shared__ float s_ea[64][5];
  __shared__ __align__(16) char s_union[2 * 64 * AS_STRIDE * 2];  // 34816 B (As | t_s alias)
  __shared__ __align__(16) u16 s_u[64 * AS_STRIDE];               // 17408 B
  u16* As = (u16*)s_union;
  float* t_s = (float*)s_union;

  const int tid = threadIdx.x;
  const int e0 = blockIdx.x * 64;
  const int w = tid >> 6, lane = tid & 63, quad = lane >> 4, l16 = lane & 15;
  const int c0w = w * 32;

  if (tid < 64) {
    int src = esrc[e0 + tid], dst = edst[e0 + tid];
    s_src[tid] = src; s_dst[tid] = dst;
    float dx = pos[dst * 3 + 0] - pos[src * 3 + 0];
    float dy = pos[dst * 3 + 1] - pos[src * 3 + 1];
    float dz = pos[dst * 3 + 2] - pos[src * 3 + 2];
    float dist = sqrtf(dx * dx + dy * dy + dz * dz) + 1e-8f;
    float inv = 1.f / dist;
    s_ea[tid][0] = dist;
    s_ea[tid][1] = dx * inv; s_ea[tid][2] = dy * inv; s_ea[tid][3] = dz * inv;
    s_ea[tid][4] = 1.f / (dist * dist + 1e-6f);
  }
  __syncthreads();

  { // stage gathered h rows (bf16), 16B per thread
    int r = tid >> 4, c8 = (tid & 15) * 8;
    #pragma unroll
    for (int rp = 0; rp < 4; rp++) {
      int m = rp * 16 + r;
      *(uint4*)(As + m * AS_STRIDE + c8) =
          *(const uint4*)(hbf + (size_t)s_dst[m] * 128 + c8);
      *(uint4*)(As + (64 + m) * AS_STRIDE + c8) =
          *(const uint4*)(hbf + (size_t)s_src[m] * 128 + c8);
    }
  }
  __syncthreads();

  f32x4 acc[4][2];
  #pragma unroll
  for (int rt = 0; rt < 4; rt++)
    #pragma unroll
    for (int ct = 0; ct < 2; ct++)
      acc[rt][ct] = (f32x4){0.f, 0.f, 0.f, 0.f};

  #pragma unroll
  for (int kk = 0; kk < 8; kk++) {               // K=256 (dst half then src half)
    const u16* Ab = As + (kk < 4 ? 0 : 64 * AS_STRIDE);
    const int kl = (kk & 3) * 32 + quad * 8;
    bf16x8 af[4];
    #pragma unroll
    for (int rt = 0; rt < 4; rt++)
      af[rt] = *(const bf16x8*)(Ab + (rt * 16 + l16) * AS_STRIDE + kl);
    const int kg = kk * 32 + quad * 8;
    #pragma unroll
    for (int ct = 0; ct < 2; ct++) {
      bf16x8 bfv = *(const bf16x8*)(W1T + (size_t)(c0w + ct * 16 + l16) * 256 + kg);
      #pragma unroll
      for (int rt = 0; rt < 4; rt++)
        acc[rt][ct] = __builtin_amdgcn_mfma_f32_16x16x32_bf16(af[rt], bfv, acc[rt][ct], 0, 0, 0);
    }
  }

  float b1v[2], w1cv[2][5];
  #pragma unroll
  for (int ct = 0; ct < 2; ct++) {
    int n = c0w + ct * 16 + l16;
    b1v[ct] = b1[n];
    #pragma unroll
    for (int k = 0; k < 5; k++) w1cv[ct][k] = w1c[k * 128 + n];
  }
  __syncthreads();  // all A-reads done; t_s aliases As

  #pragma unroll
  for (int rt = 0; rt < 4; rt++)
    #pragma unroll
    for (int ct = 0; ct < 2; ct++) {
      int n = c0w + ct * 16 + l16;
      #pragma unroll
      for (int r = 0; r < 4; r++) {
        int m = rt * 16 + quad * 4 + r;
        float v = acc[rt][ct][r] + b1v[ct];
        #pragma unroll
        for (int k = 0; k < 5; k++) v += s_ea[m][k] * w1cv[ct][k];  // fp32 ea term
        t_s[m * TS_STRIDE + n] = v;
      }
    }
  __syncthreads();

  { // LN + SiLU -> u (bf16)
    int row = tid >> 2, sub = tid & 3;
    float s = 0.f, sq = 0.f, vals[32];
    #pragma unroll
    for (int i = 0; i < 32; i++) {
      float v = t_s[row * TS_STRIDE + sub + i * 4];
      vals[i] = v; s += v; sq += v * v;
    }
    s += __shfl_xor(s, 1); sq += __shfl_xor(sq, 1);
    s += __shfl_xor(s, 2); sq += __shfl_xor(sq, 2);
    float mean = s * (1.f / 128.f);
    float rstd = rsqrtf(sq * (1.f / 128.f) - mean * mean + 1e-5f);
    #pragma unroll
    for (int i = 0; i < 32; i++) {
      int c = sub + i * 4;
      float a = (vals[i] - mean) * rstd * g[c] + be[c];
      s_u[row * AS_STRIDE + c] = f2bf(silu_f(a));
    }
  }
  __syncthreads();

  f32x4 acc2[4][2];
  #pragma unroll
  for (int rt = 0; rt < 4; rt++)
    #pragma unroll
    for (int ct = 0; ct < 2; ct++)
      acc2[rt][ct] = (f32x4){0.f, 0.f, 0.f, 0.f};

  #pragma unroll
  for (int kk = 0; kk < 4; kk++) {               // K=128
    const int kl = kk * 32 + quad * 8;
    bf16x8 af[4];
    #pragma unroll
    for (int rt = 0; rt < 4; rt++)
      af[rt] = *(const bf16x8*)(s_u + (rt * 16 + l16) * AS_STRIDE + kl);
    #pragma unroll
    for (int ct = 0; ct < 2; ct++) {
      bf16x8 bfv = *(const bf16x8*)(W2T + (size_t)(c0w + ct * 16 + l16) * 128 + kl);
      #pragma unroll
      for (int rt = 0; rt < 4; rt++)
        acc2[rt][ct] = __builtin_amdgcn_mfma_f32_16x16x32_bf16(af[rt], bfv, acc2[rt][ct], 0, 0, 0);
    }
  }

  #pragma unroll
  for (int ct = 0; ct < 2; ct++) {
    int n = c0w + ct * 16 + l16;
    float b2v = b2[n];
    #pragma unroll
    for (int rt = 0; rt < 4; rt++)
      #pragma unroll
      for (int r = 0; r < 4; r++) {
        int m = rt * 16 + quad * 4 + r;
        atomicAdd(&aggr[(size_t)s_dst[m] * 128 + n], acc2[rt][ct][r] + b2v);
      }
  }
}

// ---------------- node MLP + residual + outer LN (per layer) -----------------
__global__ __launch_bounds__(256, 2)
void node_mlp_kernel(u16* __restrict__ hbf, const float* __restrict__ aggr,
                     float* __restrict__ h,
                     const u16* __restrict__ W1T, const float* __restrict__ b1,
                     const float* __restrict__ g, const float* __restrict__ be,
                     const u16* __restrict__ W2T, const float* __restrict__ b2,
                     const float* __restrict__ lng, const float* __restrict__ lnb,
                     int Nn) {
  __shared__ __align__(16) char s_union[2 * 64 * AS_STRIDE * 2];
  __shared__ __align__(16) u16 s_u[64 * AS_STRIDE];
  u16* As = (u16*)s_union;
  float* t_s = (float*)s_union;

  const int tid = threadIdx.x;
  const int m0 = blockIdx.x * 64;
  const int w = tid >> 6, lane = tid & 63, quad = lane >> 4, l16 = lane & 15;
  const int c0w = w * 32;

  { // stage h rows (bf16 copy) + aggr rows (f32 -> bf16)
    int r = tid >> 4, c8 = (tid & 15) * 8;
    #pragma unroll
    for (int rp = 0; rp < 4; rp++) {
      int m = rp * 16 + r;
      int node = m0 + m; if (node >= Nn) node = Nn - 1;
      *(uint4*)(As + m * AS_STRIDE + c8) = *(const uint4*)(hbf + (size_t)node * 128 + c8);
      const float* ap = aggr + (size_t)node * 128 + c8;
      float4 f0 = *(const float4*)ap;
      float4 f1 = *(const float4*)(ap + 4);
      union { u16 us[8]; uint4 v; } pk;
      pk.us[0] = f2bf(f0.x); pk.us[1] = f2bf(f0.y); pk.us[2] = f2bf(f0.z); pk.us[3] = f2bf(f0.w);
      pk.us[4] = f2bf(f1.x); pk.us[5] = f2bf(f1.y); pk.us[6] = f2bf(f1.z); pk.us[7] = f2bf(f1.w);
      *(uint4*)(As + (64 + m) * AS_STRIDE + c8) = pk.v;
    }
  }
  __syncthreads();

  f32x4 acc[4][2];
  #pragma unroll
  for (int rt = 0; rt < 4; rt++)
    #pragma unroll
    for (int ct = 0; ct < 2; ct++)
      acc[rt][ct] = (f32x4){0.f, 0.f, 0.f, 0.f};

  #pragma unroll
  for (int kk = 0; kk < 8; kk++) {               // K=256 (h half then aggr half)
    const u16* Ab = As + (kk < 4 ? 0 : 64 * AS_STRIDE);
    const int kl = (kk & 3) * 32 + quad * 8;
    bf16x8 af[4];
    #pragma unroll
    for (int rt = 0; rt < 4; rt++)
      af[rt] = *(const bf16x8*)(Ab + (rt * 16 + l16) * AS_STRIDE + kl);
    const int kg = kk * 32 + quad * 8;
    #pragma unroll
    for (int ct = 0; ct < 2; ct++) {
      bf16x8 bfv = *(const bf16x8*)(W1T + (size_t)(c0w + ct * 16 + l16) * 256 + kg);
      #pragma unroll
      for (int rt = 0; rt < 4; rt++)
        acc[rt][ct] = __builtin_amdgcn_mfma_f32_16x16x32_bf16(af[rt], bfv, acc[rt][ct], 0, 0, 0);
    }
  }

  float b1v[2];
  #pragma unroll
  for (int ct = 0; ct < 2; ct++) b1v[ct] = b1[c0w + ct * 16 + l16];
  __syncthreads();

  #pragma unroll
  for (int rt = 0; rt < 4; rt++)
    #pragma unroll
    for (int ct = 0; ct < 2; ct++) {
      int n = c0w + ct * 16 + l16;
      #pragma unroll
      for (int r = 0; r < 4; r++) {
        int m = rt * 16 + quad * 4 + r;
        t_s[m * TS_STRIDE + n] = acc[rt][ct][r] + b1v[ct];
      }
    }
  __syncthreads();

  { // inner LN + SiLU -> u
    int row = tid >> 2, sub = tid & 3;
    float s = 0.f, sq = 0.f, vals[32];
    #pragma unroll
    for (int i = 0; i < 32; i++) {
      float v = t_s[row * TS_STRIDE + sub + i * 4];
      vals[i] = v; s += v; sq += v * v;
    }
    s += __shfl_xor(s, 1); sq += __shfl_xor(sq, 1);
    s += __shfl_xor(s, 2); sq += __shfl_xor(sq, 2);
    float mean = s * (1.f / 128.f);
    float rstd = rsqrtf(sq * (1.f / 128.f) - mean * mean + 1e-5f);
    #pragma unroll
    for (int i = 0; i < 32; i++) {
      int c = sub + i * 4;
      float a = (vals[i] - mean) * rstd * g[c] + be[c];
      s_u[row * AS_STRIDE + c] = f2bf(silu_f(a));
    }
  }
  __syncthreads();

  f32x4 acc2[4][2];
  #pragma unroll
  for (int rt = 0; rt < 4; rt++)
    #pragma unroll
    for (int ct = 0; ct < 2; ct++)
      acc2[rt][ct] = (f32x4){0.f, 0.f, 0.f, 0.f};

  #pragma unroll
  for (int kk = 0; kk < 4; kk++) {               // K=128
    const int kl = kk * 32 + quad * 8;
    bf16x8 af[4];
    #pragma unroll
    for (int rt = 0; rt < 4; rt++)
      af[rt] = *(const bf16x8*)(s_u + (rt * 16 + l16) * AS_STRIDE + kl);
    #pragma unroll
    for (int ct = 0; ct < 2; ct++) {
      bf16x8 bfv = *(const bf16x8*)(W2T + (size_t)(c0w + ct * 16 + l16) * 128 + kl);
      #pragma unroll
      for (int rt = 0; rt < 4; rt++)
        acc2[rt][ct] = __builtin_amdgcn_mfma_f32_16x16x32_bf16(af[rt], bfv, acc2[rt][ct], 0, 0, 0);
    }
  }

  #pragma unroll
  for (int ct = 0; ct < 2; ct++) {
    int n = c0w + ct * 16 + l16;
    float b2v = b2[n];
    #pragma unroll
    for (int rt = 0; rt < 4; rt++)
      #pragma unroll
      for (int r = 0; r < 4; r++) {
        int m = rt * 16 + quad * 4 + r;
        int node = m0 + m; if (node >= Nn) node = Nn - 1;
        t_s[m * TS_STRIDE + n] = acc2[rt][ct][r] + b2v + h[(size_t)node * 128 + n];
      }
  }
  __syncthreads();

  { // outer LN (residual already added) -> write h (f32) + hbf (bf16)
    int row = tid >> 2, sub = tid & 3;
    int node = m0 + row;
    float s = 0.f, sq = 0.f, vals[32];
    #pragma unroll
    for (int i = 0; i < 32; i++) {
      float v = t_s[row * TS_STRIDE + sub + i * 4];
      vals[i] = v; s += v; sq += v * v;
    }
    s += __shfl_xor(s, 1); sq += __shfl_xor(sq, 1);
    s += __shfl_xor(s, 2); sq += __shfl_xor(sq, 2);
    float mean = s * (1.f / 128.f);
    float rstd = rsqrtf(sq * (1.f / 128.f) - mean * mean + 1e-5f);
    if (node < Nn) {
      #pragma unroll
      for (int i = 0; i < 32; i++) {
        int c = sub + i * 4;
        float v = (vals[i] - mean) * rstd * lng[c] + lnb[c];
        h[(size_t)node * 128 + c] = v;
        hbf[(size_t)node * 128 + c] = f2bf(v);
      }
    }
  }
}

// ---------------- decoder ----------------------------------------------------
__global__ __launch_bounds__(128)
void decoder_kernel(const float* __restrict__ x, const float* __restrict__ h,
                    const float* __restrict__ w1, const float* __restrict__ b1,
                    const float* __restrict__ w2, const float* __restrict__ b2,
                    const float* __restrict__ w3, const float* __restrict__ b3,
                    float* __restrict__ out) {
  int node = blockIdx.x, j = threadIdx.x;
  __shared__ float sh[128], sd1[128], sd2[64];
  sh[j] = h[(size_t)node * 128 + j];
  __syncthreads();
  float t = b1[j];
  for (int k = 0; k < 128; k++) t += sh[k] * w1[k * 128 + j];
  sd1[j] = silu_f(t);
  __syncthreads();
  if (j < 64) {
    float t2 = b2[j];
    for (int k = 0; k < 128; k++) t2 += sd1[k] * w2[k * 64 + j];
    sd2[j] = silu_f(t2);
  }
  __syncthreads();
  if (j < 6) {
    float t3 = b3[j];
    for (int k = 0; k < 64; k++) t3 += sd2[k] * w3[k * 6 + j];
    out[(size_t)node * 6 + j] = x[node * 7 + j] + t3;
  }
}

// ---------------- host launcher ----------------------------------------------
extern "C" void kernel_launch(void* const* d_in, const int* in_sizes, int n_in,
                              void* d_out, int out_size, void* d_ws, size_t ws_size,
                              hipStream_t stream) {
  const float* x      = (const float*)d_in[0];
  const float* pos    = (const float*)d_in[1];
  const int*   eidx   = (const int*)d_in[2];
  const float* enc_w1 = (const float*)d_in[3];
  const float* enc_b1 = (const float*)d_in[4];
  const float* enc_g  = (const float*)d_in[5];
  const float* enc_be = (const float*)d_in[6];
  const float* enc_w2 = (const float*)d_in[7];
  const float* enc_b2 = (const float*)d_in[8];
  const float* e_w1   = (const float*)d_in[9];
  const float* e_b1   = (const float*)d_in[10];
  const float* e_g    = (const float*)d_in[11];
  const float* e_be   = (const float*)d_in[12];
  const float* e_w2   = (const float*)d_in[13];
  const float* e_b2   = (const float*)d_in[14];
  const float* n_w1   = (const float*)d_in[15];
  const float* n_b1   = (const float*)d_in[16];
  const float* n_g    = (const float*)d_in[17];
  const float* n_be   = (const float*)d_in[18];
  const float* n_w2   = (const float*)d_in[19];
  const float* n_b2   = (const float*)d_in[20];
  const float* ln_g   = (const float*)d_in[21];
  const float* ln_b   = (const float*)d_in[22];
  const float* dec_w1 = (const float*)d_in[23];
  const float* dec_b1 = (const float*)d_in[24];
  const float* dec_w2 = (const float*)d_in[25];
  const float* dec_b2 = (const float*)d_in[26];
  const float* dec_w3 = (const float*)d_in[27];
  const float* dec_b3 = (const float*)d_in[28];

  const int N = in_sizes[0] / 7;          // 50000
  const int E = in_sizes[2] / 2;          // 1600000

  // workspace carve (~64.6 MB)
  char* ws = (char*)d_ws;
  size_t off = 0;
  float* h    = (float*)(ws + off); off += (size_t)N * 128 * 4;   // 25,600,000
  u16*   hbf  = (u16*)(ws + off);   off += (size_t)N * 128 * 2;   // 12,800,000
  float* aggr = (float*)(ws + off); off += (size_t)N * 128 * 4;   // 25,600,000
  u16* eW1T = (u16*)(ws + off); off += 3 * 128 * 256 * 2;
  u16* eW2T = (u16*)(ws + off); off += 3 * 128 * 128 * 2;
  u16* nW1T = (u16*)(ws + off); off += 3 * 128 * 256 * 2;
  u16* nW2T = (u16*)(ws + off); off += 3 * 128 * 128 * 2;

  prep_weights<<<1152, 256, 0, stream>>>(e_w1, e_w2, n_w1, n_w2, eW1T, eW2T, nW1T, nW2T);
  encoder_kernel<<<N, 128, 0, stream>>>(x, enc_w1, enc_b1, enc_g, enc_be, enc_w2, enc_b2, h, hbf);

  for (int l = 0; l < 3; l++) {
    hipMemsetAsync(aggr, 0, (size_t)N * 128 * 4, stream);
    edge_mlp_kernel<<<E / 64, 256, 0, stream>>>(
        eidx, eidx + E, pos, hbf,
        eW1T + (size_t)l * 128 * 256,
        e_w1 + (size_t)l * 261 * 128 + 256 * 128,
        e_b1 + l * 128, e_g + l * 128, e_be + l * 128,
        eW2T + (size_t)l * 128 * 128, e_b2 + l * 128, aggr);
    node_mlp_kernel<<<(N + 63) / 64, 256, 0, stream>>>(
        hbf, aggr, h,
        nW1T + (size_t)l * 128 * 256, n_b1 + l * 128, n_g + l * 128, n_be + l * 128,
        nW2T + (size_t)l * 128 * 128, n_b2 + l * 128,
        ln_g + l * 128, ln_b + l * 128, N);
  }

  decoder_kernel<<<N, 128, 0, stream>>>(x, h, dec_w1, dec_b1, dec_w2, dec_b2, dec_w3, dec_b3,
                                        (float*)d_out);
}

// Round 2
// 2419.848 us; speedup vs baseline: 1.0946x; 1.0946x over previous
//
#include <hip/hip_runtime.h>

typedef unsigned short u16;
typedef unsigned int u32;
typedef __bf16 bf16x8 __attribute__((ext_vector_type(8)));
typedef float f32x4 __attribute__((ext_vector_type(4)));

#define AS_STRIDE 136   // bf16 elems per LDS A-row (128 + 8 pad; keeps 16B align)
#define TS_STRIDE 133   // f32 elems per LDS t-row

__device__ __forceinline__ u16 f2bf(float f) {
  union { float f; u32 u; } v; v.f = f;
  u32 r = v.u + 0x7fffu + ((v.u >> 16) & 1u);   // RNE
  return (u16)(r >> 16);
}

__device__ __forceinline__ float silu_f(float a) {
  return a / (1.f + __expf(-a));
}

// ---------------- edge sort by dst (counting sort, once per call) ------------
__global__ void edge_hist(const int* __restrict__ edst, int E, int* __restrict__ cnt) {
  int i = blockIdx.x * blockDim.x + threadIdx.x;
  if (i < E) atomicAdd(&cnt[edst[i]], 1);
}

__global__ __launch_bounds__(1024)
void scan_kernel(const int* __restrict__ cnt, int* __restrict__ cursor, int Nn) {
  __shared__ int part[1024];
  int t = threadIdx.x;
  int per = (Nn + 1023) / 1024;
  int b = t * per;
  int s = 0;
  for (int i = 0; i < per; i++) { int idx = b + i; if (idx < Nn) s += cnt[idx]; }
  part[t] = s;
  __syncthreads();
  for (int d = 1; d < 1024; d <<= 1) {
    int v = (t >= d) ? part[t - d] : 0;
    __syncthreads();
    part[t] += v;
    __syncthreads();
  }
  int excl = (t == 0) ? 0 : part[t - 1];
  for (int i = 0; i < per; i++) {
    int idx = b + i;
    if (idx < Nn) { cursor[idx] = excl; excl += cnt[idx]; }
  }
}

__global__ void edge_scatter(const int* __restrict__ esrc, const int* __restrict__ edst,
                             int E, int* __restrict__ cursor,
                             int* __restrict__ ssrc, int* __restrict__ sdst) {
  int i = blockIdx.x * blockDim.x + threadIdx.x;
  if (i < E) {
    int d = edst[i];
    int p = atomicAdd(&cursor[d], 1);
    ssrc[p] = esrc[i];
    sdst[p] = d;
  }
}

// ---------------- weight prep: transpose + bf16-cast -------------------------
__global__ void prep_weights(const float* __restrict__ e_w1, const float* __restrict__ e_w2,
                             const float* __restrict__ n_w1, const float* __restrict__ n_w2,
                             u16* __restrict__ eW1T, u16* __restrict__ eW2T,
                             u16* __restrict__ nW1T, u16* __restrict__ nW2T) {
  int i = blockIdx.x * blockDim.x + threadIdx.x;
  const int s1 = 3 * 128 * 256;
  const int s2 = 3 * 128 * 128;
  if (i < s1) {
    int l = i / 32768, r = i % 32768, n = r >> 8, k = r & 255;
    eW1T[i] = f2bf(e_w1[l * 33408 + k * 128 + n]);
  } else if (i < s1 + s2) {
    int j = i - s1; int l = j / 16384, r = j % 16384, n = r >> 7, k = r & 127;
    eW2T[j] = f2bf(e_w2[l * 16384 + k * 128 + n]);
  } else if (i < s1 + s2 + s1) {
    int j = i - s1 - s2; int l = j / 32768, r = j % 32768, n = r >> 8, k = r & 255;
    nW1T[j] = f2bf(n_w1[l * 32768 + k * 128 + n]);
  } else if (i < 2 * s1 + 2 * s2) {
    int j = i - 2 * s1 - s2; int l = j / 16384, r = j % 16384, n = r >> 7, k = r & 127;
    nW2T[j] = f2bf(n_w2[l * 16384 + k * 128 + n]);
  }
}

// ---------------- encoder ----------------------------------------------------
__global__ __launch_bounds__(128)
void encoder_kernel(const float* __restrict__ x,
                    const float* __restrict__ w1, const float* __restrict__ b1,
                    const float* __restrict__ g, const float* __restrict__ be,
                    const float* __restrict__ w2, const float* __restrict__ b2,
                    float* __restrict__ h, u16* __restrict__ hbf) {
  int node = blockIdx.x, j = threadIdx.x;
  __shared__ float sx[7];
  __shared__ float su[128];
  __shared__ float sred[4];
  if (j < 7) sx[j] = x[node * 7 + j];
  __syncthreads();
  float t = b1[j];
  #pragma unroll
  for (int k = 0; k < 7; k++) t += sx[k] * w1[k * 128 + j];
  float s = t, sq = t * t;
  for (int off = 32; off > 0; off >>= 1) { s += __shfl_down(s, off); sq += __shfl_down(sq, off); }
  int wid = j >> 6;
  if ((j & 63) == 0) { sred[wid * 2] = s; sred[wid * 2 + 1] = sq; }
  __syncthreads();
  float S = sred[0] + sred[2], SQ = sred[1] + sred[3];
  float mean = S * (1.f / 128.f);
  float rstd = rsqrtf(SQ * (1.f / 128.f) - mean * mean + 1e-5f);
  float a = (t - mean) * rstd * g[j] + be[j];
  su[j] = silu_f(a);
  __syncthreads();
  float o = b2[j];
  for (int k = 0; k < 128; k++) o += su[k] * w2[k * 128 + j];
  h[(size_t)node * 128 + j] = o;
  hbf[(size_t)node * 128 + j] = f2bf(o);
}

// ---------------- edge MLP + segmented scatter-add (per layer) ---------------
__global__ __launch_bounds__(256, 3)
void edge_mlp_kernel(const int* __restrict__ ssrc, const int* __restrict__ sdst,
                     const float* __restrict__ pos, const u16* __restrict__ hbf,
                     const u16* __restrict__ W1T,   // [128][256] bf16
                     const float* __restrict__ w1c, // [5][128] f32
                     const float* __restrict__ b1,
                     const float* __restrict__ g, const float* __restrict__ be,
                     const u16* __restrict__ W2T,   // [128][128] bf16
                     const float* __restrict__ b2,
                     float* __restrict__ aggr) {
  __shared__ int s_src[64], s_dst[64];
  __shared__ float s_ea[64][5];
  __shared__ __align__(16) char s_union[2 * 64 * AS_STRIDE * 2];  // As | t_s alias
  __shared__ __align__(16) u16 s_u[64 * AS_STRIDE];
  u16* As = (u16*)s_union;
  float* t_s = (float*)s_union;

  const int tid = threadIdx.x;
  const int e0 = blockIdx.x * 64;
  const int w = tid >> 6, lane = tid & 63, quad = lane >> 4, l16 = lane & 15;
  const int c0w = w * 32;

  if (tid < 64) {
    int src = ssrc[e0 + tid], dst = sdst[e0 + tid];
    s_src[tid] = src; s_dst[tid] = dst;
    float dx = pos[dst * 3 + 0] - pos[src * 3 + 0];
    float dy = pos[dst * 3 + 1] - pos[src * 3 + 1];
    float dz = pos[dst * 3 + 2] - pos[src * 3 + 2];
    float dist = sqrtf(dx * dx + dy * dy + dz * dz) + 1e-8f;
    float inv = 1.f / dist;
    s_ea[tid][0] = dist;
    s_ea[tid][1] = dx * inv; s_ea[tid][2] = dy * inv; s_ea[tid][3] = dz * inv;
    s_ea[tid][4] = 1.f / (dist * dist + 1e-6f);
  }
  __syncthreads();

  { // stage gathered h rows (bf16), 16B per thread
    int r = tid >> 4, c8 = (tid & 15) * 8;
    #pragma unroll
    for (int rp = 0; rp < 4; rp++) {
      int m = rp * 16 + r;
      *(uint4*)(As + m * AS_STRIDE + c8) =
          *(const uint4*)(hbf + (size_t)s_dst[m] * 128 + c8);
      *(uint4*)(As + (64 + m) * AS_STRIDE + c8) =
          *(const uint4*)(hbf + (size_t)s_src[m] * 128 + c8);
    }
  }
  __syncthreads();

  f32x4 acc[4][2];
  #pragma unroll
  for (int rt = 0; rt < 4; rt++)
    #pragma unroll
    for (int ct = 0; ct < 2; ct++)
      acc[rt][ct] = (f32x4){0.f, 0.f, 0.f, 0.f};

  #pragma unroll
  for (int kk = 0; kk < 8; kk++) {               // K=256
    const u16* Ab = As + (kk < 4 ? 0 : 64 * AS_STRIDE);
    const int kl = (kk & 3) * 32 + quad * 8;
    bf16x8 af[4];
    #pragma unroll
    for (int rt = 0; rt < 4; rt++)
      af[rt] = *(const bf16x8*)(Ab + (rt * 16 + l16) * AS_STRIDE + kl);
    const int kg = kk * 32 + quad * 8;
    #pragma unroll
    for (int ct = 0; ct < 2; ct++) {
      bf16x8 bfv = *(const bf16x8*)(W1T + (size_t)(c0w + ct * 16 + l16) * 256 + kg);
      #pragma unroll
      for (int rt = 0; rt < 4; rt++)
        acc[rt][ct] = __builtin_amdgcn_mfma_f32_16x16x32_bf16(af[rt], bfv, acc[rt][ct], 0, 0, 0);
    }
  }

  float b1v[2], w1cv[2][5];
  #pragma unroll
  for (int ct = 0; ct < 2; ct++) {
    int n = c0w + ct * 16 + l16;
    b1v[ct] = b1[n];
    #pragma unroll
    for (int k = 0; k < 5; k++) w1cv[ct][k] = w1c[k * 128 + n];
  }
  __syncthreads();  // all A-reads done; t_s aliases As

  #pragma unroll
  for (int rt = 0; rt < 4; rt++)
    #pragma unroll
    for (int ct = 0; ct < 2; ct++) {
      int n = c0w + ct * 16 + l16;
      #pragma unroll
      for (int r = 0; r < 4; r++) {
        int m = rt * 16 + quad * 4 + r;
        float v = acc[rt][ct][r] + b1v[ct];
        #pragma unroll
        for (int k = 0; k < 5; k++) v += s_ea[m][k] * w1cv[ct][k];
        t_s[m * TS_STRIDE + n] = v;
      }
    }
  __syncthreads();

  { // LN + SiLU -> u (bf16)
    int row = tid >> 2, sub = tid & 3;
    float s = 0.f, sq = 0.f, vals[32];
    #pragma unroll
    for (int i = 0; i < 32; i++) {
      float v = t_s[row * TS_STRIDE + sub + i * 4];
      vals[i] = v; s += v; sq += v * v;
    }
    s += __shfl_xor(s, 1); sq += __shfl_xor(sq, 1);
    s += __shfl_xor(s, 2); sq += __shfl_xor(sq, 2);
    float mean = s * (1.f / 128.f);
    float rstd = rsqrtf(sq * (1.f / 128.f) - mean * mean + 1e-5f);
    #pragma unroll
    for (int i = 0; i < 32; i++) {
      int c = sub + i * 4;
      float a = (vals[i] - mean) * rstd * g[c] + be[c];
      s_u[row * AS_STRIDE + c] = f2bf(silu_f(a));
    }
  }
  __syncthreads();

  f32x4 acc2[4][2];
  #pragma unroll
  for (int rt = 0; rt < 4; rt++)
    #pragma unroll
    for (int ct = 0; ct < 2; ct++)
      acc2[rt][ct] = (f32x4){0.f, 0.f, 0.f, 0.f};

  #pragma unroll
  for (int kk = 0; kk < 4; kk++) {               // K=128
    const int kl = kk * 32 + quad * 8;
    bf16x8 af[4];
    #pragma unroll
    for (int rt = 0; rt < 4; rt++)
      af[rt] = *(const bf16x8*)(s_u + (rt * 16 + l16) * AS_STRIDE + kl);
    #pragma unroll
    for (int ct = 0; ct < 2; ct++) {
      bf16x8 bfv = *(const bf16x8*)(W2T + (size_t)(c0w + ct * 16 + l16) * 128 + kl);
      #pragma unroll
      for (int rt = 0; rt < 4; rt++)
        acc2[rt][ct] = __builtin_amdgcn_mfma_f32_16x16x32_bf16(af[rt], bfv, acc2[rt][ct], 0, 0, 0);
    }
  }

  // write msg (+b2) into t_s, then segmented column-sum over sorted dst runs
  __syncthreads();  // LN phase reads of t_s alias region are long done; re-sync for reuse
  #pragma unroll
  for (int ct = 0; ct < 2; ct++) {
    int n = c0w + ct * 16 + l16;
    float b2v = b2[n];
    #pragma unroll
    for (int rt = 0; rt < 4; rt++)
      #pragma unroll
      for (int r = 0; r < 4; r++) {
        int m = rt * 16 + quad * 4 + r;
        t_s[m * TS_STRIDE + n] = acc2[rt][ct][r] + b2v;
      }
  }
  __syncthreads();

  {
    int colg = tid & 127, half = tid >> 7;
    int r0 = half * 32;
    float run = t_s[r0 * TS_STRIDE + colg];
    int cur = s_dst[r0];
    #pragma unroll 4
    for (int r = r0 + 1; r < r0 + 32; r++) {
      int d = s_dst[r];                       // wave-uniform -> no divergence
      float v = t_s[r * TS_STRIDE + colg];
      if (d != cur) {
        atomicAdd(&aggr[(size_t)cur * 128 + colg], run);
        run = 0.f; cur = d;
      }
      run += v;
    }
    atomicAdd(&aggr[(size_t)cur * 128 + colg], run);
  }
}

// ---------------- node MLP + residual + outer LN (per layer) -----------------
__global__ __launch_bounds__(256, 3)
void node_mlp_kernel(u16* __restrict__ hbf, const float* __restrict__ aggr,
                     float* __restrict__ h,
                     const u16* __restrict__ W1T, const float* __restrict__ b1,
                     const float* __restrict__ g, const float* __restrict__ be,
                     const u16* __restrict__ W2T, const float* __restrict__ b2,
                     const float* __restrict__ lng, const float* __restrict__ lnb,
                     int Nn) {
  __shared__ __align__(16) char s_union[2 * 64 * AS_STRIDE * 2];
  __shared__ __align__(16) u16 s_u[64 * AS_STRIDE];
  u16* As = (u16*)s_union;
  float* t_s = (float*)s_union;

  const int tid = threadIdx.x;
  const int m0 = blockIdx.x * 64;
  const int w = tid >> 6, lane = tid & 63, quad = lane >> 4, l16 = lane & 15;
  const int c0w = w * 32;

  {
    int r = tid >> 4, c8 = (tid & 15) * 8;
    #pragma unroll
    for (int rp = 0; rp < 4; rp++) {
      int m = rp * 16 + r;
      int node = m0 + m; if (node >= Nn) node = Nn - 1;
      *(uint4*)(As + m * AS_STRIDE + c8) = *(const uint4*)(hbf + (size_t)node * 128 + c8);
      const float* ap = aggr + (size_t)node * 128 + c8;
      float4 f0 = *(const float4*)ap;
      float4 f1 = *(const float4*)(ap + 4);
      union { u16 us[8]; uint4 v; } pk;
      pk.us[0] = f2bf(f0.x); pk.us[1] = f2bf(f0.y); pk.us[2] = f2bf(f0.z); pk.us[3] = f2bf(f0.w);
      pk.us[4] = f2bf(f1.x); pk.us[5] = f2bf(f1.y); pk.us[6] = f2bf(f1.z); pk.us[7] = f2bf(f1.w);
      *(uint4*)(As + (64 + m) * AS_STRIDE + c8) = pk.v;
    }
  }
  __syncthreads();

  f32x4 acc[4][2];
  #pragma unroll
  for (int rt = 0; rt < 4; rt++)
    #pragma unroll
    for (int ct = 0; ct < 2; ct++)
      acc[rt][ct] = (f32x4){0.f, 0.f, 0.f, 0.f};

  #pragma unroll
  for (int kk = 0; kk < 8; kk++) {
    const u16* Ab = As + (kk < 4 ? 0 : 64 * AS_STRIDE);
    const int kl = (kk & 3) * 32 + quad * 8;
    bf16x8 af[4];
    #pragma unroll
    for (int rt = 0; rt < 4; rt++)
      af[rt] = *(const bf16x8*)(Ab + (rt * 16 + l16) * AS_STRIDE + kl);
    const int kg = kk * 32 + quad * 8;
    #pragma unroll
    for (int ct = 0; ct < 2; ct++) {
      bf16x8 bfv = *(const bf16x8*)(W1T + (size_t)(c0w + ct * 16 + l16) * 256 + kg);
      #pragma unroll
      for (int rt = 0; rt < 4; rt++)
        acc[rt][ct] = __builtin_amdgcn_mfma_f32_16x16x32_bf16(af[rt], bfv, acc[rt][ct], 0, 0, 0);
    }
  }

  float b1v[2];
  #pragma unroll
  for (int ct = 0; ct < 2; ct++) b1v[ct] = b1[c0w + ct * 16 + l16];
  __syncthreads();

  #pragma unroll
  for (int rt = 0; rt < 4; rt++)
    #pragma unroll
    for (int ct = 0; ct < 2; ct++) {
      int n = c0w + ct * 16 + l16;
      #pragma unroll
      for (int r = 0; r < 4; r++) {
        int m = rt * 16 + quad * 4 + r;
        t_s[m * TS_STRIDE + n] = acc[rt][ct][r] + b1v[ct];
      }
    }
  __syncthreads();

  {
    int row = tid >> 2, sub = tid & 3;
    float s = 0.f, sq = 0.f, vals[32];
    #pragma unroll
    for (int i = 0; i < 32; i++) {
      float v = t_s[row * TS_STRIDE + sub + i * 4];
      vals[i] = v; s += v; sq += v * v;
    }
    s += __shfl_xor(s, 1); sq += __shfl_xor(sq, 1);
    s += __shfl_xor(s, 2); sq += __shfl_xor(sq, 2);
    float mean = s * (1.f / 128.f);
    float rstd = rsqrtf(sq * (1.f / 128.f) - mean * mean + 1e-5f);
    #pragma unroll
    for (int i = 0; i < 32; i++) {
      int c = sub + i * 4;
      float a = (vals[i] - mean) * rstd * g[c] + be[c];
      s_u[row * AS_STRIDE + c] = f2bf(silu_f(a));
    }
  }
  __syncthreads();

  f32x4 acc2[4][2];
  #pragma unroll
  for (int rt = 0; rt < 4; rt++)
    #pragma unroll
    for (int ct = 0; ct < 2; ct++)
      acc2[rt][ct] = (f32x4){0.f, 0.f, 0.f, 0.f};

  #pragma unroll
  for (int kk = 0; kk < 4; kk++) {
    const int kl = kk * 32 + quad * 8;
    bf16x8 af[4];
    #pragma unroll
    for (int rt = 0; rt < 4; rt++)
      af[rt] = *(const bf16x8*)(s_u + (rt * 16 + l16) * AS_STRIDE + kl);
    #pragma unroll
    for (int ct = 0; ct < 2; ct++) {
      bf16x8 bfv = *(const bf16x8*)(W2T + (size_t)(c0w + ct * 16 + l16) * 128 + kl);
      #pragma unroll
      for (int rt = 0; rt < 4; rt++)
        acc2[rt][ct] = __builtin_amdgcn_mfma_f32_16x16x32_bf16(af[rt], bfv, acc2[rt][ct], 0, 0, 0);
    }
  }

  #pragma unroll
  for (int ct = 0; ct < 2; ct++) {
    int n = c0w + ct * 16 + l16;
    float b2v = b2[n];
    #pragma unroll
    for (int rt = 0; rt < 4; rt++)
      #pragma unroll
      for (int r = 0; r < 4; r++) {
        int m = rt * 16 + quad * 4 + r;
        int node = m0 + m; if (node >= Nn) node = Nn - 1;
        t_s[m * TS_STRIDE + n] = acc2[rt][ct][r] + b2v + h[(size_t)node * 128 + n];
      }
  }
  __syncthreads();

  {
    int row = tid >> 2, sub = tid & 3;
    int node = m0 + row;
    float s = 0.f, sq = 0.f, vals[32];
    #pragma unroll
    for (int i = 0; i < 32; i++) {
      float v = t_s[row * TS_STRIDE + sub + i * 4];
      vals[i] = v; s += v; sq += v * v;
    }
    s += __shfl_xor(s, 1); sq += __shfl_xor(sq, 1);
    s += __shfl_xor(s, 2); sq += __shfl_xor(sq, 2);
    float mean = s * (1.f / 128.f);
    float rstd = rsqrtf(sq * (1.f / 128.f) - mean * mean + 1e-5f);
    if (node < Nn) {
      #pragma unroll
      for (int i = 0; i < 32; i++) {
        int c = sub + i * 4;
        float v = (vals[i] - mean) * rstd * lng[c] + lnb[c];
        h[(size_t)node * 128 + c] = v;
        hbf[(size_t)node * 128 + c] = f2bf(v);
      }
    }
  }
}

// ---------------- decoder ----------------------------------------------------
__global__ __launch_bounds__(128)
void decoder_kernel(const float* __restrict__ x, const float* __restrict__ h,
                    const float* __restrict__ w1, const float* __restrict__ b1,
                    const float* __restrict__ w2, const float* __restrict__ b2,
                    const float* __restrict__ w3, const float* __restrict__ b3,
                    float* __restrict__ out) {
  int node = blockIdx.x, j = threadIdx.x;
  __shared__ float sh[128], sd1[128], sd2[64];
  sh[j] = h[(size_t)node * 128 + j];
  __syncthreads();
  float t = b1[j];
  for (int k = 0; k < 128; k++) t += sh[k] * w1[k * 128 + j];
  sd1[j] = silu_f(t);
  __syncthreads();
  if (j < 64) {
    float t2 = b2[j];
    for (int k = 0; k < 128; k++) t2 += sd1[k] * w2[k * 64 + j];
    sd2[j] = silu_f(t2);
  }
  __syncthreads();
  if (j < 6) {
    float t3 = b3[j];
    for (int k = 0; k < 64; k++) t3 += sd2[k] * w3[k * 6 + j];
    out[(size_t)node * 6 + j] = x[node * 7 + j] + t3;
  }
}

// ---------------- host launcher ----------------------------------------------
extern "C" void kernel_launch(void* const* d_in, const int* in_sizes, int n_in,
                              void* d_out, int out_size, void* d_ws, size_t ws_size,
                              hipStream_t stream) {
  const float* x      = (const float*)d_in[0];
  const float* pos    = (const float*)d_in[1];
  const int*   eidx   = (const int*)d_in[2];
  const float* enc_w1 = (const float*)d_in[3];
  const float* enc_b1 = (const float*)d_in[4];
  const float* enc_g  = (const float*)d_in[5];
  const float* enc_be = (const float*)d_in[6];
  const float* enc_w2 = (const float*)d_in[7];
  const float* enc_b2 = (const float*)d_in[8];
  const float* e_w1   = (const float*)d_in[9];
  const float* e_b1   = (const float*)d_in[10];
  const float* e_g    = (const float*)d_in[11];
  const float* e_be   = (const float*)d_in[12];
  const float* e_w2   = (const float*)d_in[13];
  const float* e_b2   = (const float*)d_in[14];
  const float* n_w1   = (const float*)d_in[15];
  const float* n_b1   = (const float*)d_in[16];
  const float* n_g    = (const float*)d_in[17];
  const float* n_be   = (const float*)d_in[18];
  const float* n_w2   = (const float*)d_in[19];
  const float* n_b2   = (const float*)d_in[20];
  const float* ln_g   = (const float*)d_in[21];
  const float* ln_b   = (const float*)d_in[22];
  const float* dec_w1 = (const float*)d_in[23];
  const float* dec_b1 = (const float*)d_in[24];
  const float* dec_w2 = (const float*)d_in[25];
  const float* dec_b2 = (const float*)d_in[26];
  const float* dec_w3 = (const float*)d_in[27];
  const float* dec_b3 = (const float*)d_in[28];

  const int N = in_sizes[0] / 7;          // 50000
  const int E = in_sizes[2] / 2;          // 1600000

  // workspace carve (~78 MB)
  char* ws = (char*)d_ws;
  size_t off = 0;
  float* h    = (float*)(ws + off); off += (size_t)N * 128 * 4;
  u16*   hbf  = (u16*)(ws + off);   off += (size_t)N * 128 * 2;
  float* aggr = (float*)(ws + off); off += (size_t)N * 128 * 4;
  u16* eW1T = (u16*)(ws + off); off += 3 * 128 * 256 * 2;
  u16* eW2T = (u16*)(ws + off); off += 3 * 128 * 128 * 2;
  u16* nW1T = (u16*)(ws + off); off += 3 * 128 * 256 * 2;
  u16* nW2T = (u16*)(ws + off); off += 3 * 128 * 128 * 2;
  int* cnt    = (int*)(ws + off); off += (size_t)N * 4;
  int* cursor = (int*)(ws + off); off += (size_t)N * 4;
  int* ssrc   = (int*)(ws + off); off += (size_t)E * 4;
  int* sdst   = (int*)(ws + off); off += (size_t)E * 4;

  // sort edges by dst once (reused across all 3 layers)
  hipMemsetAsync(cnt, 0, (size_t)N * 4, stream);
  edge_hist<<<(E + 255) / 256, 256, 0, stream>>>(eidx + E, E, cnt);
  scan_kernel<<<1, 1024, 0, stream>>>(cnt, cursor, N);
  edge_scatter<<<(E + 255) / 256, 256, 0, stream>>>(eidx, eidx + E, E, cursor, ssrc, sdst);

  prep_weights<<<1152, 256, 0, stream>>>(e_w1, e_w2, n_w1, n_w2, eW1T, eW2T, nW1T, nW2T);
  encoder_kernel<<<N, 128, 0, stream>>>(x, enc_w1, enc_b1, enc_g, enc_be, enc_w2, enc_b2, h, hbf);

  for (int l = 0; l < 3; l++) {
    hipMemsetAsync(aggr, 0, (size_t)N * 128 * 4, stream);
    edge_mlp_kernel<<<E / 64, 256, 0, stream>>>(
        ssrc, sdst, pos, hbf,
        eW1T + (size_t)l * 128 * 256,
        e_w1 + (size_t)l * 261 * 128 + 256 * 128,
        e_b1 + l * 128, e_g + l * 128, e_be + l * 128,
        eW2T + (size_t)l * 128 * 128, e_b2 + l * 128, aggr);
    node_mlp_kernel<<<(N + 63) / 64, 256, 0, stream>>>(
        hbf, aggr, h,
        nW1T + (size_t)l * 128 * 256, n_b1 + l * 128, n_g + l * 128, n_be + l * 128,
        nW2T + (size_t)l * 128 * 128, n_b2 + l * 128,
        ln_g + l * 128, ln_b + l * 128, N);
  }

  decoder_kernel<<<N, 128, 0, stream>>>(x, h, dec_w1, dec_b1, dec_w2, dec_b2, dec_w3, dec_b3,
                                        (float*)d_out);
}

// Round 3
// 1642.954 us; speedup vs baseline: 1.6121x; 1.4729x over previous
//
#include <hip/hip_runtime.h>

typedef unsigned short u16;
typedef unsigned int u32;
typedef __bf16 bf16x8 __attribute__((ext_vector_type(8)));
typedef float f32x4 __attribute__((ext_vector_type(4)));

#define AS_STRIDE 136   // bf16 elems per LDS A-row (128 + 8 pad; 16B-aligned rows)
#define TS_STRIDE 133   // f32 elems per LDS t-row

__device__ __forceinline__ u16 f2bf(float f) {
  union { float f; u32 u; } v; v.f = f;
  u32 r = v.u + 0x7fffu + ((v.u >> 16) & 1u);   // RNE
  return (u16)(r >> 16);
}

__device__ __forceinline__ float bf2f(u16 u) {
  union { u32 u; float f; } v; v.u = ((u32)u) << 16; return v.f;
}

__device__ __forceinline__ float silu_f(float a) {
  return a / (1.f + __expf(-a));
}

// ---------------- edge sort by dst (counting sort, once per call) ------------
__global__ void edge_hist(const int* __restrict__ edst, int E, int* __restrict__ cnt) {
  int i = blockIdx.x * blockDim.x + threadIdx.x;
  if (i < E) atomicAdd(&cnt[edst[i]], 1);
}

__global__ __launch_bounds__(1024)
void scan_kernel(const int* __restrict__ cnt, int* __restrict__ cursor, int Nn) {
  __shared__ int part[1024];
  int t = threadIdx.x;
  int per = (Nn + 1023) / 1024;
  int b = t * per;
  int s = 0;
  for (int i = 0; i < per; i++) { int idx = b + i; if (idx < Nn) s += cnt[idx]; }
  part[t] = s;
  __syncthreads();
  for (int d = 1; d < 1024; d <<= 1) {
    int v = (t >= d) ? part[t - d] : 0;
    __syncthreads();
    part[t] += v;
    __syncthreads();
  }
  int excl = (t == 0) ? 0 : part[t - 1];
  for (int i = 0; i < per; i++) {
    int idx = b + i;
    if (idx < Nn) { cursor[idx] = excl; excl += cnt[idx]; }
  }
}

__global__ void edge_scatter(const int* __restrict__ esrc, const int* __restrict__ edst,
                             int E, int* __restrict__ cursor,
                             int* __restrict__ ssrc, int* __restrict__ sdst) {
  int i = blockIdx.x * blockDim.x + threadIdx.x;
  if (i < E) {
    int d = edst[i];
    int p = atomicAdd(&cursor[d], 1);
    ssrc[p] = esrc[i];
    sdst[p] = d;
  }
}

// ---------------- weight prep: transpose + bf16-cast -------------------------
__global__ void prep_weights(const float* __restrict__ e_w1, const float* __restrict__ e_w2,
                             const float* __restrict__ n_w1, const float* __restrict__ n_w2,
                             u16* __restrict__ eW1T, u16* __restrict__ eW2T,
                             u16* __restrict__ nW1T, u16* __restrict__ nW2T) {
  int i = blockIdx.x * blockDim.x + threadIdx.x;
  const int s1 = 3 * 128 * 256;
  const int s2 = 3 * 128 * 128;
  if (i < s1) {
    int l = i / 32768, r = i % 32768, n = r >> 8, k = r & 255;
    eW1T[i] = f2bf(e_w1[l * 33408 + k * 128 + n]);
  } else if (i < s1 + s2) {
    int j = i - s1; int l = j / 16384, r = j % 16384, n = r >> 7, k = r & 127;
    eW2T[j] = f2bf(e_w2[l * 16384 + k * 128 + n]);
  } else if (i < s1 + s2 + s1) {
    int j = i - s1 - s2; int l = j / 32768, r = j % 32768, n = r >> 8, k = r & 255;
    nW1T[j] = f2bf(n_w1[l * 32768 + k * 128 + n]);
  } else if (i < 2 * s1 + 2 * s2) {
    int j = i - 2 * s1 - s2; int l = j / 16384, r = j % 16384, n = r >> 7, k = r & 127;
    nW2T[j] = f2bf(n_w2[l * 16384 + k * 128 + n]);
  }
}

// ---------------- encoder ----------------------------------------------------
__global__ __launch_bounds__(128)
void encoder_kernel(const float* __restrict__ x,
                    const float* __restrict__ w1, const float* __restrict__ b1,
                    const float* __restrict__ g, const float* __restrict__ be,
                    const float* __restrict__ w2, const float* __restrict__ b2,
                    u16* __restrict__ hbf) {
  int node = blockIdx.x, j = threadIdx.x;
  __shared__ float sx[7];
  __shared__ float su[128];
  __shared__ float sred[4];
  if (j < 7) sx[j] = x[node * 7 + j];
  __syncthreads();
  float t = b1[j];
  #pragma unroll
  for (int k = 0; k < 7; k++) t += sx[k] * w1[k * 128 + j];
  float s = t, sq = t * t;
  for (int off = 32; off > 0; off >>= 1) { s += __shfl_down(s, off); sq += __shfl_down(sq, off); }
  int wid = j >> 6;
  if ((j & 63) == 0) { sred[wid * 2] = s; sred[wid * 2 + 1] = sq; }
  __syncthreads();
  float S = sred[0] + sred[2], SQ = sred[1] + sred[3];
  float mean = S * (1.f / 128.f);
  float rstd = rsqrtf(SQ * (1.f / 128.f) - mean * mean + 1e-5f);
  float a = (t - mean) * rstd * g[j] + be[j];
  su[j] = silu_f(a);
  __syncthreads();
  float o = b2[j];
  for (int k = 0; k < 128; k++) o += su[k] * w2[k * 128 + j];
  hbf[(size_t)node * 128 + j] = f2bf(o);
}

// ---------------- per-layer precompute: hd = h@W1d + b1, hs = h@W1s ----------
__global__ __launch_bounds__(256, 4)
void precompute_hds(const u16* __restrict__ hbf,
                    const u16* __restrict__ W1T,   // [128][256] (n,k) bf16
                    const float* __restrict__ b1,
                    u16* __restrict__ hd_all, u16* __restrict__ hs_all, int Nn) {
  __shared__ __align__(16) u16 As[64 * AS_STRIDE];
  const int tid = threadIdx.x;
  const int m0 = blockIdx.x * 64;
  const int w = tid >> 6, lane = tid & 63, quad = lane >> 4, l16 = lane & 15;
  const int c0w = w * 32;

  { // stage 64 h rows (bf16)
    int r = tid >> 4, c8 = (tid & 15) * 8;
    #pragma unroll
    for (int rp = 0; rp < 4; rp++) {
      int m = rp * 16 + r;
      int node = m0 + m; if (node >= Nn) node = Nn - 1;
      *(uint4*)(As + m * AS_STRIDE + c8) = *(const uint4*)(hbf + (size_t)node * 128 + c8);
    }
  }
  __syncthreads();

  f32x4 ad[4][2], as2[4][2];
  #pragma unroll
  for (int rt = 0; rt < 4; rt++)
    #pragma unroll
    for (int ct = 0; ct < 2; ct++) {
      ad[rt][ct] = (f32x4){0.f, 0.f, 0.f, 0.f};
      as2[rt][ct] = (f32x4){0.f, 0.f, 0.f, 0.f};
    }

  #pragma unroll
  for (int kk = 0; kk < 4; kk++) {
    const int kl = kk * 32 + quad * 8;
    bf16x8 af[4];
    #pragma unroll
    for (int rt = 0; rt < 4; rt++)
      af[rt] = *(const bf16x8*)(As + (rt * 16 + l16) * AS_STRIDE + kl);
    #pragma unroll
    for (int ct = 0; ct < 2; ct++) {
      const u16* wb = W1T + (size_t)(c0w + ct * 16 + l16) * 256;
      bf16x8 bd = *(const bf16x8*)(wb + kl);
      bf16x8 bs = *(const bf16x8*)(wb + 128 + kl);
      #pragma unroll
      for (int rt = 0; rt < 4; rt++) {
        ad[rt][ct]  = __builtin_amdgcn_mfma_f32_16x16x32_bf16(af[rt], bd, ad[rt][ct], 0, 0, 0);
        as2[rt][ct] = __builtin_amdgcn_mfma_f32_16x16x32_bf16(af[rt], bs, as2[rt][ct], 0, 0, 0);
      }
    }
  }

  #pragma unroll
  for (int ct = 0; ct < 2; ct++) {
    int n = c0w + ct * 16 + l16;
    float b1v = b1[n];
    #pragma unroll
    for (int rt = 0; rt < 4; rt++)
      #pragma unroll
      for (int r = 0; r < 4; r++) {
        int m = rt * 16 + quad * 4 + r;
        int node = m0 + m;
        if (node < Nn) {
          size_t base = (size_t)node * 128 + n;
          hd_all[base] = f2bf(ad[rt][ct][r] + b1v);
          hs_all[base] = f2bf(as2[rt][ct][r]);
        }
      }
  }
}

// ---------------- edge MLP (gather+LN fused, single MFMA) + seg scatter-add --
__global__ __launch_bounds__(256, 4)
void edge_mlp_kernel(const int* __restrict__ ssrc, const int* __restrict__ sdst,
                     const float* __restrict__ pos,
                     const u16* __restrict__ hd_all, const u16* __restrict__ hs_all,
                     const float* __restrict__ w1c, // [5][128] f32
                     const float* __restrict__ g, const float* __restrict__ be,
                     const u16* __restrict__ W2T,   // [128][128] bf16
                     const float* __restrict__ b2,
                     float* __restrict__ aggr) {
  __shared__ int s_src[64], s_dst[64];
  __shared__ float s_ea[64][5];
  __shared__ __align__(16) char s_un[64 * TS_STRIDE * 4];  // 34,048 B: t_s; s_u aliases
  float* t_s = (float*)s_un;
  u16*   s_u = (u16*)s_un;

  const int tid = threadIdx.x;
  const int e0 = blockIdx.x * 64;
  const int w = tid >> 6, lane = tid & 63, quad = lane >> 4, l16 = lane & 15;
  const int c0w = w * 32;

  if (tid < 64) {
    int src = ssrc[e0 + tid], dst = sdst[e0 + tid];
    s_src[tid] = src; s_dst[tid] = dst;
    float dx = pos[dst * 3 + 0] - pos[src * 3 + 0];
    float dy = pos[dst * 3 + 1] - pos[src * 3 + 1];
    float dz = pos[dst * 3 + 2] - pos[src * 3 + 2];
    float dist = sqrtf(dx * dx + dy * dy + dz * dz) + 1e-8f;
    float inv = 1.f / dist;
    s_ea[tid][0] = dist;
    s_ea[tid][1] = dx * inv; s_ea[tid][2] = dy * inv; s_ea[tid][3] = dz * inv;
    s_ea[tid][4] = 1.f / (dist * dist + 1e-6f);
  }
  __syncthreads();

  { // phase A: t = hd[dst] + hs[src] + ea@w1c; LN+SiLU in registers -> s_u
    const int rg = tid >> 4, cg = tid & 15;
    const int c0 = cg * 8;
    float wcf[5][8], gf[8], bef[8];
    #pragma unroll
    for (int k = 0; k < 5; k++) {
      *(f32x4*)&wcf[k][0] = *(const f32x4*)(w1c + k * 128 + c0);
      *(f32x4*)&wcf[k][4] = *(const f32x4*)(w1c + k * 128 + c0 + 4);
    }
    *(f32x4*)&gf[0]  = *(const f32x4*)(g + c0);
    *(f32x4*)&gf[4]  = *(const f32x4*)(g + c0 + 4);
    *(f32x4*)&bef[0] = *(const f32x4*)(be + c0);
    *(f32x4*)&bef[4] = *(const f32x4*)(be + c0 + 4);

    #pragma unroll
    for (int rr = 0; rr < 4; rr++) {
      int m = rg * 4 + rr;
      int d = s_dst[m], sidx = s_src[m];
      bf16x8 hd8 = *(const bf16x8*)(hd_all + (size_t)d * 128 + c0);
      bf16x8 hs8 = *(const bf16x8*)(hs_all + (size_t)sidx * 128 + c0);
      float ea0 = s_ea[m][0], ea1 = s_ea[m][1], ea2 = s_ea[m][2],
            ea3 = s_ea[m][3], ea4 = s_ea[m][4];
      float t[8];
      #pragma unroll
      for (int j = 0; j < 8; j++) {
        t[j] = (float)hd8[j] + (float)hs8[j]
             + ea0 * wcf[0][j] + ea1 * wcf[1][j] + ea2 * wcf[2][j]
             + ea3 * wcf[3][j] + ea4 * wcf[4][j];
      }
      float sm = 0.f, sq = 0.f;
      #pragma unroll
      for (int j = 0; j < 8; j++) { sm += t[j]; sq += t[j] * t[j]; }
      sm += __shfl_xor(sm, 1);  sq += __shfl_xor(sq, 1);
      sm += __shfl_xor(sm, 2);  sq += __shfl_xor(sq, 2);
      sm += __shfl_xor(sm, 4);  sq += __shfl_xor(sq, 4);
      sm += __shfl_xor(sm, 8);  sq += __shfl_xor(sq, 8);
      float mean = sm * (1.f / 128.f);
      float rstd = rsqrtf(sq * (1.f / 128.f) - mean * mean + 1e-5f);
      union { u16 us[8]; uint4 v; } pk;
      #pragma unroll
      for (int j = 0; j < 8; j++) {
        float a = (t[j] - mean) * rstd * gf[j] + bef[j];
        pk.us[j] = f2bf(silu_f(a));
      }
      *(uint4*)(s_u + m * AS_STRIDE + c0) = pk.v;
    }
  }
  __syncthreads();

  f32x4 acc2[4][2];
  #pragma unroll
  for (int rt = 0; rt < 4; rt++)
    #pragma unroll
    for (int ct = 0; ct < 2; ct++)
      acc2[rt][ct] = (f32x4){0.f, 0.f, 0.f, 0.f};

  #pragma unroll
  for (int kk = 0; kk < 4; kk++) {               // K=128
    const int kl = kk * 32 + quad * 8;
    bf16x8 af[4];
    #pragma unroll
    for (int rt = 0; rt < 4; rt++)
      af[rt] = *(const bf16x8*)(s_u + (rt * 16 + l16) * AS_STRIDE + kl);
    #pragma unroll
    for (int ct = 0; ct < 2; ct++) {
      bf16x8 bfv = *(const bf16x8*)(W2T + (size_t)(c0w + ct * 16 + l16) * 128 + kl);
      #pragma unroll
      for (int rt = 0; rt < 4; rt++)
        acc2[rt][ct] = __builtin_amdgcn_mfma_f32_16x16x32_bf16(af[rt], bfv, acc2[rt][ct], 0, 0, 0);
    }
  }
  __syncthreads();  // s_u reads done; t_s reuses the region

  #pragma unroll
  for (int ct = 0; ct < 2; ct++) {
    int n = c0w + ct * 16 + l16;
    float b2v = b2[n];
    #pragma unroll
    for (int rt = 0; rt < 4; rt++)
      #pragma unroll
      for (int r = 0; r < 4; r++) {
        int m = rt * 16 + quad * 4 + r;
        t_s[m * TS_STRIDE + n] = acc2[rt][ct][r] + b2v;
      }
  }
  __syncthreads();

  { // segmented column-sum over sorted dst runs
    int colg = tid & 127, half = tid >> 7;
    int r0 = half * 32;
    float run = t_s[r0 * TS_STRIDE + colg];
    int cur = s_dst[r0];
    #pragma unroll 4
    for (int r = r0 + 1; r < r0 + 32; r++) {
      int d = s_dst[r];
      float v = t_s[r * TS_STRIDE + colg];
      if (d != cur) {
        atomicAdd(&aggr[(size_t)cur * 128 + colg], run);
        run = 0.f; cur = d;
      }
      run += v;
    }
    atomicAdd(&aggr[(size_t)cur * 128 + colg], run);
  }
}

// ---------------- node MLP + residual + outer LN (per layer) -----------------
__global__ __launch_bounds__(256, 3)
void node_mlp_kernel(u16* __restrict__ hbf, const float* __restrict__ aggr,
                     const u16* __restrict__ W1T, const float* __restrict__ b1,
                     const float* __restrict__ g, const float* __restrict__ be,
                     const u16* __restrict__ W2T, const float* __restrict__ b2,
                     const float* __restrict__ lng, const float* __restrict__ lnb,
                     int Nn) {
  __shared__ __align__(16) char s_union[2 * 64 * AS_STRIDE * 2];
  __shared__ __align__(16) u16 s_u[64 * AS_STRIDE];
  u16* As = (u16*)s_union;
  float* t_s = (float*)s_union;

  const int tid = threadIdx.x;
  const int m0 = blockIdx.x * 64;
  const int w = tid >> 6, lane = tid & 63, quad = lane >> 4, l16 = lane & 15;
  const int c0w = w * 32;

  {
    int r = tid >> 4, c8 = (tid & 15) * 8;
    #pragma unroll
    for (int rp = 0; rp < 4; rp++) {
      int m = rp * 16 + r;
      int node = m0 + m; if (node >= Nn) node = Nn - 1;
      *(uint4*)(As + m * AS_STRIDE + c8) = *(const uint4*)(hbf + (size_t)node * 128 + c8);
      const float* ap = aggr + (size_t)node * 128 + c8;
      float4 f0 = *(const float4*)ap;
      float4 f1 = *(const float4*)(ap + 4);
      union { u16 us[8]; uint4 v; } pk;
      pk.us[0] = f2bf(f0.x); pk.us[1] = f2bf(f0.y); pk.us[2] = f2bf(f0.z); pk.us[3] = f2bf(f0.w);
      pk.us[4] = f2bf(f1.x); pk.us[5] = f2bf(f1.y); pk.us[6] = f2bf(f1.z); pk.us[7] = f2bf(f1.w);
      *(uint4*)(As + (64 + m) * AS_STRIDE + c8) = pk.v;
    }
  }
  __syncthreads();

  f32x4 acc[4][2];
  #pragma unroll
  for (int rt = 0; rt < 4; rt++)
    #pragma unroll
    for (int ct = 0; ct < 2; ct++)
      acc[rt][ct] = (f32x4){0.f, 0.f, 0.f, 0.f};

  #pragma unroll
  for (int kk = 0; kk < 8; kk++) {
    const u16* Ab = As + (kk < 4 ? 0 : 64 * AS_STRIDE);
    const int kl = (kk & 3) * 32 + quad * 8;
    bf16x8 af[4];
    #pragma unroll
    for (int rt = 0; rt < 4; rt++)
      af[rt] = *(const bf16x8*)(Ab + (rt * 16 + l16) * AS_STRIDE + kl);
    const int kg = kk * 32 + quad * 8;
    #pragma unroll
    for (int ct = 0; ct < 2; ct++) {
      bf16x8 bfv = *(const bf16x8*)(W1T + (size_t)(c0w + ct * 16 + l16) * 256 + kg);
      #pragma unroll
      for (int rt = 0; rt < 4; rt++)
        acc[rt][ct] = __builtin_amdgcn_mfma_f32_16x16x32_bf16(af[rt], bfv, acc[rt][ct], 0, 0, 0);
    }
  }

  float b1v[2];
  #pragma unroll
  for (int ct = 0; ct < 2; ct++) b1v[ct] = b1[c0w + ct * 16 + l16];
  __syncthreads();

  #pragma unroll
  for (int rt = 0; rt < 4; rt++)
    #pragma unroll
    for (int ct = 0; ct < 2; ct++) {
      int n = c0w + ct * 16 + l16;
      #pragma unroll
      for (int r = 0; r < 4; r++) {
        int m = rt * 16 + quad * 4 + r;
        t_s[m * TS_STRIDE + n] = acc[rt][ct][r] + b1v[ct];
      }
    }
  __syncthreads();

  {
    int row = tid >> 2, sub = tid & 3;
    float s = 0.f, sq = 0.f, vals[32];
    #pragma unroll
    for (int i = 0; i < 32; i++) {
      float v = t_s[row * TS_STRIDE + sub + i * 4];
      vals[i] = v; s += v; sq += v * v;
    }
    s += __shfl_xor(s, 1); sq += __shfl_xor(sq, 1);
    s += __shfl_xor(s, 2); sq += __shfl_xor(sq, 2);
    float mean = s * (1.f / 128.f);
    float rstd = rsqrtf(sq * (1.f / 128.f) - mean * mean + 1e-5f);
    #pragma unroll
    for (int i = 0; i < 32; i++) {
      int c = sub + i * 4;
      float a = (vals[i] - mean) * rstd * g[c] + be[c];
      s_u[row * AS_STRIDE + c] = f2bf(silu_f(a));
    }
  }
  __syncthreads();

  f32x4 acc2[4][2];
  #pragma unroll
  for (int rt = 0; rt < 4; rt++)
    #pragma unroll
    for (int ct = 0; ct < 2; ct++)
      acc2[rt][ct] = (f32x4){0.f, 0.f, 0.f, 0.f};

  #pragma unroll
  for (int kk = 0; kk < 4; kk++) {
    const int kl = kk * 32 + quad * 8;
    bf16x8 af[4];
    #pragma unroll
    for (int rt = 0; rt < 4; rt++)
      af[rt] = *(const bf16x8*)(s_u + (rt * 16 + l16) * AS_STRIDE + kl);
    #pragma unroll
    for (int ct = 0; ct < 2; ct++) {
      bf16x8 bfv = *(const bf16x8*)(W2T + (size_t)(c0w + ct * 16 + l16) * 128 + kl);
      #pragma unroll
      for (int rt = 0; rt < 4; rt++)
        acc2[rt][ct] = __builtin_amdgcn_mfma_f32_16x16x32_bf16(af[rt], bfv, acc2[rt][ct], 0, 0, 0);
    }
  }

  #pragma unroll
  for (int ct = 0; ct < 2; ct++) {
    int n = c0w + ct * 16 + l16;
    float b2v = b2[n];
    #pragma unroll
    for (int rt = 0; rt < 4; rt++)
      #pragma unroll
      for (int r = 0; r < 4; r++) {
        int m = rt * 16 + quad * 4 + r;
        int node = m0 + m; if (node >= Nn) node = Nn - 1;
        t_s[m * TS_STRIDE + n] = acc2[rt][ct][r] + b2v + bf2f(hbf[(size_t)node * 128 + n]);
      }
  }
  __syncthreads();

  {
    int row = tid >> 2, sub = tid & 3;
    int node = m0 + row;
    float s = 0.f, sq = 0.f, vals[32];
    #pragma unroll
    for (int i = 0; i < 32; i++) {
      float v = t_s[row * TS_STRIDE + sub + i * 4];
      vals[i] = v; s += v; sq += v * v;
    }
    s += __shfl_xor(s, 1); sq += __shfl_xor(sq, 1);
    s += __shfl_xor(s, 2); sq += __shfl_xor(sq, 2);
    float mean = s * (1.f / 128.f);
    float rstd = rsqrtf(sq * (1.f / 128.f) - mean * mean + 1e-5f);
    if (node < Nn) {
      #pragma unroll
      for (int i = 0; i < 32; i++) {
        int c = sub + i * 4;
        float v = (vals[i] - mean) * rstd * lng[c] + lnb[c];
        hbf[(size_t)node * 128 + c] = f2bf(v);
      }
    }
  }
}

// ---------------- decoder ----------------------------------------------------
__global__ __launch_bounds__(128)
void decoder_kernel(const float* __restrict__ x, const u16* __restrict__ hbf,
                    const float* __restrict__ w1, const float* __restrict__ b1,
                    const float* __restrict__ w2, const float* __restrict__ b2,
                    const float* __restrict__ w3, const float* __restrict__ b3,
                    float* __restrict__ out) {
  int node = blockIdx.x, j = threadIdx.x;
  __shared__ float sh[128], sd1[128], sd2[64];
  sh[j] = bf2f(hbf[(size_t)node * 128 + j]);
  __syncthreads();
  float t = b1[j];
  for (int k = 0; k < 128; k++) t += sh[k] * w1[k * 128 + j];
  sd1[j] = silu_f(t);
  __syncthreads();
  if (j < 64) {
    float t2 = b2[j];
    for (int k = 0; k < 128; k++) t2 += sd1[k] * w2[k * 64 + j];
    sd2[j] = silu_f(t2);
  }
  __syncthreads();
  if (j < 6) {
    float t3 = b3[j];
    for (int k = 0; k < 64; k++) t3 += sd2[k] * w3[k * 6 + j];
    out[(size_t)node * 6 + j] = x[node * 7 + j] + t3;
  }
}

// ---------------- host launcher ----------------------------------------------
extern "C" void kernel_launch(void* const* d_in, const int* in_sizes, int n_in,
                              void* d_out, int out_size, void* d_ws, size_t ws_size,
                              hipStream_t stream) {
  const float* x      = (const float*)d_in[0];
  const float* pos    = (const float*)d_in[1];
  const int*   eidx   = (const int*)d_in[2];
  const float* enc_w1 = (const float*)d_in[3];
  const float* enc_b1 = (const float*)d_in[4];
  const float* enc_g  = (const float*)d_in[5];
  const float* enc_be = (const float*)d_in[6];
  const float* enc_w2 = (const float*)d_in[7];
  const float* enc_b2 = (const float*)d_in[8];
  const float* e_w1   = (const float*)d_in[9];
  const float* e_b1   = (const float*)d_in[10];
  const float* e_g    = (const float*)d_in[11];
  const float* e_be   = (const float*)d_in[12];
  const float* e_w2   = (const float*)d_in[13];
  const float* e_b2   = (const float*)d_in[14];
  const float* n_w1   = (const float*)d_in[15];
  const float* n_b1   = (const float*)d_in[16];
  const float* n_g    = (const float*)d_in[17];
  const float* n_be   = (const float*)d_in[18];
  const float* n_w2   = (const float*)d_in[19];
  const float* n_b2   = (const float*)d_in[20];
  const float* ln_g   = (const float*)d_in[21];
  const float* ln_b   = (const float*)d_in[22];
  const float* dec_w1 = (const float*)d_in[23];
  const float* dec_b1 = (const float*)d_in[24];
  const float* dec_w2 = (const float*)d_in[25];
  const float* dec_b2 = (const float*)d_in[26];
  const float* dec_w3 = (const float*)d_in[27];
  const float* dec_b3 = (const float*)d_in[28];

  const int N = in_sizes[0] / 7;          // 50000
  const int E = in_sizes[2] / 2;          // 1600000

  // workspace carve (~78 MB)
  char* ws = (char*)d_ws;
  size_t off = 0;
  u16*   hbf    = (u16*)(ws + off);   off += (size_t)N * 128 * 2;   // 12.8 MB
  u16*   hd_all = (u16*)(ws + off);   off += (size_t)N * 128 * 2;   // 12.8 MB
  u16*   hs_all = (u16*)(ws + off);   off += (size_t)N * 128 * 2;   // 12.8 MB
  float* aggr   = (float*)(ws + off); off += (size_t)N * 128 * 4;   // 25.6 MB
  u16* eW1T = (u16*)(ws + off); off += 3 * 128 * 256 * 2;
  u16* eW2T = (u16*)(ws + off); off += 3 * 128 * 128 * 2;
  u16* nW1T = (u16*)(ws + off); off += 3 * 128 * 256 * 2;
  u16* nW2T = (u16*)(ws + off); off += 3 * 128 * 128 * 2;
  int* cnt    = (int*)(ws + off); off += (size_t)N * 4;
  int* cursor = (int*)(ws + off); off += (size_t)N * 4;
  int* ssrc   = (int*)(ws + off); off += (size_t)E * 4;
  int* sdst   = (int*)(ws + off); off += (size_t)E * 4;

  // sort edges by dst once (reused across all 3 layers)
  hipMemsetAsync(cnt, 0, (size_t)N * 4, stream);
  edge_hist<<<(E + 255) / 256, 256, 0, stream>>>(eidx + E, E, cnt);
  scan_kernel<<<1, 1024, 0, stream>>>(cnt, cursor, N);
  edge_scatter<<<(E + 255) / 256, 256, 0, stream>>>(eidx, eidx + E, E, cursor, ssrc, sdst);

  prep_weights<<<1152, 256, 0, stream>>>(e_w1, e_w2, n_w1, n_w2, eW1T, eW2T, nW1T, nW2T);
  encoder_kernel<<<N, 128, 0, stream>>>(x, enc_w1, enc_b1, enc_g, enc_be, enc_w2, enc_b2, hbf);

  const int nblk = (N + 63) / 64;
  for (int l = 0; l < 3; l++) {
    hipMemsetAsync(aggr, 0, (size_t)N * 128 * 4, stream);
    precompute_hds<<<nblk, 256, 0, stream>>>(
        hbf, eW1T + (size_t)l * 128 * 256, e_b1 + l * 128, hd_all, hs_all, N);
    edge_mlp_kernel<<<E / 64, 256, 0, stream>>>(
        ssrc, sdst, pos, hd_all, hs_all,
        e_w1 + (size_t)l * 261 * 128 + 256 * 128,
        e_g + l * 128, e_be + l * 128,
        eW2T + (size_t)l * 128 * 128, e_b2 + l * 128, aggr);
    node_mlp_kernel<<<nblk, 256, 0, stream>>>(
        hbf, aggr,
        nW1T + (size_t)l * 128 * 256, n_b1 + l * 128, n_g + l * 128, n_be + l * 128,
        nW2T + (size_t)l * 128 * 128, n_b2 + l * 128,
        ln_g + l * 128, ln_b + l * 128, N);
  }

  decoder_kernel<<<N, 128, 0, stream>>>(x, hbf, dec_w1, dec_b1, dec_w2, dec_b2, dec_w3, dec_b3,
                                        (float*)d_out);
}